// Round 1
// baseline (334.563 us; speedup 1.0000x reference)
//
#include <hip/hip_runtime.h>
#include <hip/hip_bf16.h>
#include <math.h>

#define B_ 2
#define L_ 2048
#define D_ 1024
#define N_ 16
#define CCH 32   // chunks over L
#define TCH 64   // chunk length  (CCH*TCH == L_)

__device__ __forceinline__ float softplusf(float z) {
  return fmaxf(z, 0.f) + log1pf(__expf(-fabsf(z)));
}

// ---------------- K1: partial sums over t-chunks for gc = mean_L(x) ----------
__global__ __launch_bounds__(256) void k_gc_partial(const float* __restrict__ x,
                                                    float* __restrict__ part) {
  int blk = blockIdx.x;            // b*32 + lc
  int b = blk >> 5, lc = blk & 31;
  int tid = threadIdx.x;
  float s0 = 0.f, s1 = 0.f, s2 = 0.f, s3 = 0.f;
  int tbase = b * L_ + lc * 64;
  for (int s = 0; s < 64; ++s) {
    const float* row = x + (size_t)(tbase + s) * D_;
    s0 += row[tid];
    s1 += row[tid + 256];
    s2 += row[tid + 512];
    s3 += row[tid + 768];
  }
  float* p = part + (size_t)blk * D_;
  p[tid] = s0; p[tid + 256] = s1; p[tid + 512] = s2; p[tid + 768] = s3;
}

// ---------------- K2: reduce partials -> gc, liquid scaler -> new_h [B,N] ----
__global__ __launch_bounds__(256) void k_newh(const float* __restrict__ part,
    const float* __restrict__ Wi_W, const float* __restrict__ Wi_b,
    const float* __restrict__ Wr_W, const float* __restrict__ tau,
    const float* __restrict__ h0, float* __restrict__ newh) {
  __shared__ float gcs[B_ * D_];
  int tid = threadIdx.x;
  for (int idx = tid; idx < B_ * D_; idx += 256) {
    int b = idx >> 10, d = idx & (D_ - 1);
    float s = 0.f;
    for (int lc = 0; lc < 32; ++lc) s += part[(size_t)((b << 5) | lc) * D_ + d];
    gcs[idx] = s * (1.f / L_);
  }
  __syncthreads();
  if (tid < B_ * N_) {
    int b = tid >> 4, n = tid & 15;
    float inp = Wi_b[n];
    const float* g = gcs + b * D_;
    const float* w = Wi_W + n * D_;
    for (int d = 0; d < D_; d += 4) {
      float4 gv = *(const float4*)(g + d);
      float4 wv = *(const float4*)(w + d);
      inp += gv.x * wv.x + gv.y * wv.y + gv.z * wv.z + gv.w * wv.w;
    }
    float rec = 0.f;
    for (int m = 0; m < N_; ++m) rec += h0[m] * Wr_W[n * N_ + m];
    float th = tanhf(inp + rec);
    float tc = fminf(fmaxf(tau[n], 0.1f), 10.f);
    float cur = h0[n];
    newh[tid] = cur + 0.1f * ((th - cur) / tc);   // DT = 0.1
  }
}

// ---------------- K3: sel[b,d] = sigmoid(new_h @ sel_W.T + sel_b) ------------
__global__ __launch_bounds__(256) void k_sel(const float* __restrict__ newh,
    const float* __restrict__ sel_W, const float* __restrict__ sel_b,
    float* __restrict__ sel) {
  int gid = blockIdx.x * 256 + threadIdx.x;   // over B*D
  int b = gid >> 10, d = gid & (D_ - 1);
  const float* w = sel_W + d * N_;
  const float* h = newh + b * N_;
  float z = sel_b[d];
  #pragma unroll
  for (int n = 0; n < N_; n += 4) {
    float4 wv = *(const float4*)(w + n);
    z += h[n] * wv.x + h[n + 1] * wv.y + h[n + 2] * wv.z + h[n + 3] * wv.w;
  }
  sel[gid] = 1.f / (1.f + __expf(-z));
}

// ---------------- K4: delta = softplus(xs @ delta_W.T + delta_b + dt_bias) ---
// fp32 tiled GEMM: 64x64 block tile, 256 threads, 4x4 per thread, K-step 32.
__global__ __launch_bounds__(256) void k_delta_gemm(const float* __restrict__ x,
    const float* __restrict__ sel, const float* __restrict__ W,
    const float* __restrict__ delta_b, const float* __restrict__ dt_bias,
    float* __restrict__ delta) {
  __shared__ float As[32][68];   // [kk][row]  (+4 pad)
  __shared__ float Bs[32][68];
  int i0 = blockIdx.x * 64;
  int j0 = blockIdx.y * 64;
  int b = i0 / L_;               // tile never crosses batch boundary (64 | 2048)
  int tid = threadIdx.x;
  int tx = tid & 15, ty = tid >> 4;
  int lrow = tid >> 2;
  int lk = (tid & 3) << 3;
  float acc[4][4] = {};
  const float* sbase = sel + b * D_;
  for (int k0 = 0; k0 < D_; k0 += 32) {
    const float* ap = x + (size_t)(i0 + lrow) * D_ + k0 + lk;
    const float* sp = sbase + k0 + lk;
    const float* bp = W + (size_t)(j0 + lrow) * D_ + k0 + lk;
    float4 a0 = *(const float4*)ap;
    float4 a1 = *(const float4*)(ap + 4);
    float4 s0 = *(const float4*)sp;
    float4 s1 = *(const float4*)(sp + 4);
    float4 b0 = *(const float4*)bp;
    float4 b1 = *(const float4*)(bp + 4);
    As[lk + 0][lrow] = a0.x * s0.x; As[lk + 1][lrow] = a0.y * s0.y;
    As[lk + 2][lrow] = a0.z * s0.z; As[lk + 3][lrow] = a0.w * s0.w;
    As[lk + 4][lrow] = a1.x * s1.x; As[lk + 5][lrow] = a1.y * s1.y;
    As[lk + 6][lrow] = a1.z * s1.z; As[lk + 7][lrow] = a1.w * s1.w;
    Bs[lk + 0][lrow] = b0.x; Bs[lk + 1][lrow] = b0.y;
    Bs[lk + 2][lrow] = b0.z; Bs[lk + 3][lrow] = b0.w;
    Bs[lk + 4][lrow] = b1.x; Bs[lk + 5][lrow] = b1.y;
    Bs[lk + 6][lrow] = b1.z; Bs[lk + 7][lrow] = b1.w;
    __syncthreads();
    #pragma unroll
    for (int kk = 0; kk < 32; ++kk) {
      float4 av = *(const float4*)&As[kk][ty << 2];
      float4 bv = *(const float4*)&Bs[kk][tx << 2];
      float am[4] = {av.x, av.y, av.z, av.w};
      float bn[4] = {bv.x, bv.y, bv.z, bv.w};
      #pragma unroll
      for (int m = 0; m < 4; ++m)
        #pragma unroll
        for (int n = 0; n < 4; ++n)
          acc[m][n] += am[m] * bn[n];
    }
    __syncthreads();
  }
  #pragma unroll
  for (int m = 0; m < 4; ++m) {
    int i = i0 + (ty << 2) + m;
    #pragma unroll
    for (int n = 0; n < 4; ++n) {
      int j = j0 + (tx << 2) + n;
      float z = acc[m][n] + delta_b[j] + dt_bias[j];
      delta[(size_t)i * D_ + j] = softplusf(z);
    }
  }
}

// ---------------- K5: Bm = xs@B_W.T + B_b ; Cm = xs@C_W.T + C_b --------------
// 4 rows per block; one wave per row; row staged in LDS; k split in halves.
__global__ __launch_bounds__(256) void k_bmcm(const float* __restrict__ x,
    const float* __restrict__ sel,
    const float* __restrict__ B_W, const float* __restrict__ B_b,
    const float* __restrict__ C_W, const float* __restrict__ C_b,
    float* __restrict__ Bm, float* __restrict__ Cm) {
  __shared__ float xsr[4][D_];
  int sub = threadIdx.x >> 6;
  int lane = threadIdx.x & 63;
  int r = blockIdx.x * 4 + sub;
  int b = r / L_;
  const float* xr = x + (size_t)r * D_;
  const float* sr = sel + b * D_;
  #pragma unroll
  for (int kb = 0; kb < 4; ++kb) {
    int k = kb * 256 + lane * 4;
    float4 xv = *(const float4*)(xr + k);
    float4 sv = *(const float4*)(sr + k);
    xsr[sub][k + 0] = xv.x * sv.x;
    xsr[sub][k + 1] = xv.y * sv.y;
    xsr[sub][k + 2] = xv.z * sv.z;
    xsr[sub][k + 3] = xv.w * sv.w;
  }
  __syncthreads();
  int o = lane & 31, half = lane >> 5;
  const float* w = (o < N_) ? (B_W + o * D_) : (C_W + (o - N_) * D_);
  float acc = 0.f;
  int k0 = half * 512;
  for (int k = 0; k < 512; k += 4) {
    float4 wv = *(const float4*)(w + k0 + k);
    acc += xsr[sub][k0 + k] * wv.x + xsr[sub][k0 + k + 1] * wv.y
         + xsr[sub][k0 + k + 2] * wv.z + xsr[sub][k0 + k + 3] * wv.w;
  }
  acc += __shfl_down(acc, 32, 64);
  if (half == 0) {
    if (o < N_) Bm[r * N_ + o] = acc + B_b[o];
    else        Cm[r * N_ + (o - N_)] = acc + C_b[o - N_];
  }
}

// ---------------- K6: scan pass 1 — per-chunk local scan + decay product -----
// thread = (b, c, d); 16 states in registers; layout of outputs: [b,c,d,n]
__global__ __launch_bounds__(256) void k_scan1(const float* __restrict__ x,
    const float* __restrict__ sel, const float* __restrict__ delta,
    const float* __restrict__ Bm, const float* __restrict__ A_log,
    float* __restrict__ prodA, float* __restrict__ hend) {
  int gid = blockIdx.x * 256 + threadIdx.x;   // (b*CCH + c)*D_ + d
  int d = gid & (D_ - 1);
  int b = gid >> 15;                          // / (CCH*D_)
  int c = (gid >> 10) & (CCH - 1);
  float A[N_], rA[N_];
  unsigned smallm = 0;
  #pragma unroll
  for (int n = 0; n < N_; ++n) {
    float a = -__expf(A_log[d * N_ + n]);
    A[n] = a;
    rA[n] = 1.f / a;
    if (fabsf(a) < 1e-6f) smallm |= (1u << n);
  }
  float selv = sel[b * D_ + d];
  float h[N_], p[N_];
  #pragma unroll
  for (int n = 0; n < N_; ++n) { h[n] = 0.f; p[n] = 1.f; }
  int t0 = c * TCH;
  for (int s = 0; s < TCH; ++s) {
    int row = b * L_ + t0 + s;
    size_t idx = (size_t)row * D_ + d;
    float dlt = delta[idx];
    float xv = x[idx] * selv;
    const float4* bmp = (const float4*)(Bm + (size_t)row * N_);
    float4 q0 = bmp[0], q1 = bmp[1], q2 = bmp[2], q3 = bmp[3];
    float bmv[N_] = {q0.x,q0.y,q0.z,q0.w, q1.x,q1.y,q1.z,q1.w,
                     q2.x,q2.y,q2.z,q2.w, q3.x,q3.y,q3.z,q3.w};
    #pragma unroll
    for (int n = 0; n < N_; ++n) {
      float Ad = __expf(A[n] * dlt);
      float f = ((smallm >> n) & 1u) ? dlt : (Ad - 1.f) * rA[n];
      h[n] = Ad * h[n] + (f * bmv[n]) * xv;
      p[n] *= Ad;
    }
  }
  float4* pp = (float4*)(prodA + (size_t)gid * N_);
  float4* hp = (float4*)(hend + (size_t)gid * N_);
  pp[0] = make_float4(p[0], p[1], p[2], p[3]);
  pp[1] = make_float4(p[4], p[5], p[6], p[7]);
  pp[2] = make_float4(p[8], p[9], p[10], p[11]);
  pp[3] = make_float4(p[12], p[13], p[14], p[15]);
  hp[0] = make_float4(h[0], h[1], h[2], h[3]);
  hp[1] = make_float4(h[4], h[5], h[6], h[7]);
  hp[2] = make_float4(h[8], h[9], h[10], h[11]);
  hp[3] = make_float4(h[12], h[13], h[14], h[15]);
}

// ---------------- K7: scan pass 2 — cross-chunk prefix (per b,d,n) -----------
__global__ __launch_bounds__(256) void k_scan2(const float* __restrict__ prodA,
    const float* __restrict__ hend, float* __restrict__ hin) {
  int gid = blockIdx.x * 256 + threadIdx.x;   // over B*D*N = 32768
  int b = gid >> 14;
  int rem = gid & 16383;                      // d*N + n
  float H = 0.f;
  for (int c = 0; c < CCH; ++c) {
    size_t idx = ((size_t)(b * CCH + c) << 14) + rem;
    hin[idx] = H;                             // carry-in for chunk c
    H = prodA[idx] * H + hend[idx];
  }
}

// ---------------- K8: scan pass 3 — re-scan with carry-in, emit y ------------
__global__ __launch_bounds__(256) void k_scan3(const float* __restrict__ x,
    const float* __restrict__ sel, const float* __restrict__ delta,
    const float* __restrict__ Bm, const float* __restrict__ Cm,
    const float* __restrict__ A_log, const float* __restrict__ hin,
    float* __restrict__ out) {
  int gid = blockIdx.x * 256 + threadIdx.x;
  int d = gid & (D_ - 1);
  int b = gid >> 15;
  int c = (gid >> 10) & (CCH - 1);
  float A[N_], rA[N_];
  unsigned smallm = 0;
  #pragma unroll
  for (int n = 0; n < N_; ++n) {
    float a = -__expf(A_log[d * N_ + n]);
    A[n] = a;
    rA[n] = 1.f / a;
    if (fabsf(a) < 1e-6f) smallm |= (1u << n);
  }
  float selv = sel[b * D_ + d];
  float h[N_];
  {
    const float4* hp = (const float4*)(hin + (size_t)gid * N_);
    float4 v0 = hp[0], v1 = hp[1], v2 = hp[2], v3 = hp[3];
    h[0]=v0.x; h[1]=v0.y; h[2]=v0.z; h[3]=v0.w;
    h[4]=v1.x; h[5]=v1.y; h[6]=v1.z; h[7]=v1.w;
    h[8]=v2.x; h[9]=v2.y; h[10]=v2.z; h[11]=v2.w;
    h[12]=v3.x; h[13]=v3.y; h[14]=v3.z; h[15]=v3.w;
  }
  int t0 = c * TCH;
  for (int s = 0; s < TCH; ++s) {
    int row = b * L_ + t0 + s;
    size_t idx = (size_t)row * D_ + d;
    float dlt = delta[idx];
    float xv = x[idx] * selv;
    const float4* bmp = (const float4*)(Bm + (size_t)row * N_);
    float4 q0 = bmp[0], q1 = bmp[1], q2 = bmp[2], q3 = bmp[3];
    float bmv[N_] = {q0.x,q0.y,q0.z,q0.w, q1.x,q1.y,q1.z,q1.w,
                     q2.x,q2.y,q2.z,q2.w, q3.x,q3.y,q3.z,q3.w};
    const float4* cmp = (const float4*)(Cm + (size_t)row * N_);
    float4 r0 = cmp[0], r1 = cmp[1], r2 = cmp[2], r3 = cmp[3];
    float cmv[N_] = {r0.x,r0.y,r0.z,r0.w, r1.x,r1.y,r1.z,r1.w,
                     r2.x,r2.y,r2.z,r2.w, r3.x,r3.y,r3.z,r3.w};
    float y = 0.f;
    #pragma unroll
    for (int n = 0; n < N_; ++n) {
      float Ad = __expf(A[n] * dlt);
      float f = ((smallm >> n) & 1u) ? dlt : (Ad - 1.f) * rA[n];
      h[n] = Ad * h[n] + (f * bmv[n]) * xv;
      y += h[n] * cmv[n];
    }
    out[idx] = y;
  }
}

extern "C" void kernel_launch(void* const* d_in, const int* in_sizes, int n_in,
                              void* d_out, int out_size, void* d_ws, size_t ws_size,
                              hipStream_t stream) {
  const float* x       = (const float*)d_in[0];
  const float* deltaW  = (const float*)d_in[1];
  const float* deltab  = (const float*)d_in[2];
  const float* B_W     = (const float*)d_in[3];
  const float* B_b     = (const float*)d_in[4];
  const float* C_W     = (const float*)d_in[5];
  const float* C_b     = (const float*)d_in[6];
  const float* A_log   = (const float*)d_in[7];
  const float* dt_bias = (const float*)d_in[8];
  const float* tau     = (const float*)d_in[9];
  const float* Wi_W    = (const float*)d_in[10];
  const float* Wi_b    = (const float*)d_in[11];
  const float* Wr_W    = (const float*)d_in[12];
  const float* sel_W   = (const float*)d_in[13];
  const float* sel_b   = (const float*)d_in[14];
  const float* h0      = (const float*)d_in[15];
  float* out = (float*)d_out;

  float* ws    = (float*)d_ws;          // ~30.2 MB total
  float* delta = ws;                    // B*L*D      = 4194304
  float* Bm    = delta + 4194304;       // B*L*N      = 65536
  float* Cm    = Bm + 65536;            // 65536
  float* part  = Cm + 65536;            // B*32*D     = 65536
  float* newh  = part + 65536;          // 64
  float* selp  = newh + 64;             // B*D        = 2048
  float* prodA = selp + 2048;           // B*CCH*D*N  = 1048576
  float* hend  = prodA + 1048576;       // 1048576
  float* hin   = hend + 1048576;        // 1048576

  hipLaunchKernelGGL(k_gc_partial, dim3(64), dim3(256), 0, stream, x, part);
  hipLaunchKernelGGL(k_newh, dim3(1), dim3(256), 0, stream,
                     part, Wi_W, Wi_b, Wr_W, tau, h0, newh);
  hipLaunchKernelGGL(k_sel, dim3(8), dim3(256), 0, stream,
                     newh, sel_W, sel_b, selp);
  hipLaunchKernelGGL(k_delta_gemm, dim3(64, 16), dim3(256), 0, stream,
                     x, selp, deltaW, deltab, dt_bias, delta);
  hipLaunchKernelGGL(k_bmcm, dim3(1024), dim3(256), 0, stream,
                     x, selp, B_W, B_b, C_W, C_b, Bm, Cm);
  hipLaunchKernelGGL(k_scan1, dim3(256), dim3(256), 0, stream,
                     x, selp, delta, Bm, A_log, prodA, hend);
  hipLaunchKernelGGL(k_scan2, dim3(128), dim3(256), 0, stream,
                     prodA, hend, hin);
  hipLaunchKernelGGL(k_scan3, dim3(256), dim3(256), 0, stream,
                     x, selp, delta, Bm, Cm, A_log, hin, out);
}

// Round 2
// 239.379 us; speedup vs baseline: 1.3976x; 1.3976x over previous
//
#include <hip/hip_runtime.h>
#include <hip/hip_bf16.h>
#include <math.h>

#define B_ 2
#define L_ 2048
#define D_ 1024
#define N_ 16
#define CCH 64   // chunks over L
#define TCH 32   // chunk length  (CCH*TCH == L_)
#define NCOLS 1056   // D_ + 2*N_
#define NPAD  1152   // 9 * 128

typedef unsigned short u16;
typedef __attribute__((ext_vector_type(8))) short short8v;
typedef __attribute__((ext_vector_type(8))) unsigned short ushort8v;
typedef __attribute__((ext_vector_type(4))) float f32x4;

__device__ __forceinline__ float softplusf(float z) {
  return fmaxf(z, 0.f) + log1pf(__expf(-fabsf(z)));
}

__device__ __forceinline__ u16 bf16rne(float f) {
  union { float f; unsigned u; } c; c.f = f;
  unsigned u = c.u;
  u += 0x7fffu + ((u >> 16) & 1u);
  return (u16)(u >> 16);
}

__device__ __forceinline__ void gl_lds16(const void* g, void* l) {
  __builtin_amdgcn_global_load_lds(
      (const __attribute__((address_space(1))) void*)g,
      (__attribute__((address_space(3))) void*)l, 16, 0, 0);
}

// ---------------- K1: partial sums over t-chunks for gc = mean_L(x) ----------
__global__ __launch_bounds__(256) void k_gc_partial(const float* __restrict__ x,
                                                    float* __restrict__ part) {
  int blk = blockIdx.x;            // b*32 + lc
  int b = blk >> 5, lc = blk & 31;
  int tid = threadIdx.x;
  float s0 = 0.f, s1 = 0.f, s2 = 0.f, s3 = 0.f;
  int tbase = b * L_ + lc * 64;
  for (int s = 0; s < 64; ++s) {
    const float* row = x + (size_t)(tbase + s) * D_;
    s0 += row[tid];
    s1 += row[tid + 256];
    s2 += row[tid + 512];
    s3 += row[tid + 768];
  }
  float* p = part + (size_t)blk * D_;
  p[tid] = s0; p[tid + 256] = s1; p[tid + 512] = s2; p[tid + 768] = s3;
}

// ---------------- K2: reduce partials -> gc, liquid scaler -> new_h [B,N] ----
__global__ __launch_bounds__(256) void k_newh(const float* __restrict__ part,
    const float* __restrict__ Wi_W, const float* __restrict__ Wi_b,
    const float* __restrict__ Wr_W, const float* __restrict__ tau,
    const float* __restrict__ h0, float* __restrict__ newh) {
  __shared__ float gcs[B_ * D_];
  int tid = threadIdx.x;
  for (int idx = tid; idx < B_ * D_; idx += 256) {
    int b = idx >> 10, d = idx & (D_ - 1);
    float s = 0.f;
    for (int lc = 0; lc < 32; ++lc) s += part[(size_t)((b << 5) | lc) * D_ + d];
    gcs[idx] = s * (1.f / L_);
  }
  __syncthreads();
  if (tid < B_ * N_) {
    int b = tid >> 4, n = tid & 15;
    float inp = Wi_b[n];
    const float* g = gcs + b * D_;
    const float* w = Wi_W + n * D_;
    for (int d = 0; d < D_; d += 4) {
      float4 gv = *(const float4*)(g + d);
      float4 wv = *(const float4*)(w + d);
      inp += gv.x * wv.x + gv.y * wv.y + gv.z * wv.z + gv.w * wv.w;
    }
    float rec = 0.f;
    for (int m = 0; m < N_; ++m) rec += h0[m] * Wr_W[n * N_ + m];
    float th = tanhf(inp + rec);
    float tc = fminf(fmaxf(tau[n], 0.1f), 10.f);
    float cur = h0[n];
    newh[tid] = cur + 0.1f * ((th - cur) / tc);   // DT = 0.1
  }
}

// ---------------- K3: sel[b,d] = sigmoid(new_h @ sel_W.T + sel_b) ------------
__global__ __launch_bounds__(256) void k_sel(const float* __restrict__ newh,
    const float* __restrict__ sel_W, const float* __restrict__ sel_b,
    float* __restrict__ sel) {
  int gid = blockIdx.x * 256 + threadIdx.x;   // over B*D
  int b = gid >> 10, d = gid & (D_ - 1);
  const float* w = sel_W + d * N_;
  const float* h = newh + b * N_;
  float z = sel_b[d];
  #pragma unroll
  for (int n = 0; n < N_; n += 4) {
    float4 wv = *(const float4*)(w + n);
    z += h[n] * wv.x + h[n + 1] * wv.y + h[n + 2] * wv.z + h[n + 3] * wv.w;
  }
  sel[gid] = 1.f / (1.f + __expf(-z));
}

// ---------------- K4a: pack x -> bf16 ----------------------------------------
__global__ __launch_bounds__(256) void k_pack_x(const float* __restrict__ x,
                                                u16* __restrict__ xb) {
  int gid = blockIdx.x * 256 + threadIdx.x;    // 524288 threads, 8 elems each
  const float4* xp = (const float4*)x + (size_t)gid * 2;
  float4 v0 = xp[0], v1 = xp[1];
  ushort8v r;
  r[0] = bf16rne(v0.x); r[1] = bf16rne(v0.y);
  r[2] = bf16rne(v0.z); r[3] = bf16rne(v0.w);
  r[4] = bf16rne(v1.x); r[5] = bf16rne(v1.y);
  r[6] = bf16rne(v1.z); r[7] = bf16rne(v1.w);
  *(ushort8v*)(xb + (size_t)gid * 8) = r;
}

// ---------------- K4b: pack [delta_W; B_W; C_W] * sel(b) -> bf16 -------------
__global__ __launch_bounds__(256) void k_pack_w(const float* __restrict__ dW,
    const float* __restrict__ B_W, const float* __restrict__ C_W,
    const float* __restrict__ sel, u16* __restrict__ Wp) {
  int gid = blockIdx.x * 256 + threadIdx.x;    // 147456 threads, 8 elems each
  int b = blockIdx.y;
  size_t e = (size_t)gid * 8;                  // < 1179648
  int nn = (int)(e >> 10);
  int k = (int)(e & 1023);
  ushort8v r;
  if (nn < NCOLS) {
    const float* src = (nn < 1024) ? dW + (size_t)nn * 1024
                     : (nn < 1040) ? B_W + (size_t)(nn - 1024) * 1024
                                   : C_W + (size_t)(nn - 1040) * 1024;
    float4 s0 = *(const float4*)(src + k);
    float4 s1 = *(const float4*)(src + k + 4);
    const float* sp = sel + b * D_ + k;
    float4 e0 = *(const float4*)sp;
    float4 e1 = *(const float4*)(sp + 4);
    r[0] = bf16rne(s0.x * e0.x); r[1] = bf16rne(s0.y * e0.y);
    r[2] = bf16rne(s0.z * e0.z); r[3] = bf16rne(s0.w * e0.w);
    r[4] = bf16rne(s1.x * e1.x); r[5] = bf16rne(s1.y * e1.y);
    r[6] = bf16rne(s1.z * e1.z); r[7] = bf16rne(s1.w * e1.w);
  } else {
    r = (ushort8v)0;
  }
  *(ushort8v*)(Wp + (size_t)b * (NPAD * 1024) + e) = r;
}

// ---------------- K5: MFMA GEMM  C[4096 x 1152] = xb @ Wp^T ------------------
// 128x128 tile, BK=32, 4 waves (2x2), double-buffered LDS via global_load_lds.
// Epilogue: cols<1024 -> softplus -> delta; 1024..1039 -> Bm; 1040..1055 -> Cm.
__global__ __launch_bounds__(256) void k_gemm(
    const u16* __restrict__ xb, const u16* __restrict__ Wp,
    const float* __restrict__ delta_b, const float* __restrict__ dt_bias,
    const float* __restrict__ B_b, const float* __restrict__ C_b,
    float* __restrict__ delta, float* __restrict__ Bm, float* __restrict__ Cm) {
  __shared__ __align__(16) u16 At[2][128 * 32];
  __shared__ __align__(16) u16 Bt[2][128 * 32];
  int m0 = blockIdx.x * 128;
  int n0 = blockIdx.y * 128;
  int batch = blockIdx.x >> 4;                 // 16 m-tiles per batch
  const u16* wbase = Wp + (size_t)batch * (NPAD * 1024);
  int tid = threadIdx.x;
  int w = tid >> 6, l = tid & 63;
  int wr = w >> 1, wc = w & 1;
  // staging geometry: site (w,q) covers bytes [q*4096 + w*1024, +1024)
  int srow = (l >> 2);                         // + q*64 + w*16
  int skcol = (l & 3) * 8;                     // ushort col within 32

  f32x4 acc[4][4];
  #pragma unroll
  for (int m = 0; m < 4; ++m)
    #pragma unroll
    for (int n = 0; n < 4; ++n)
      acc[m][n] = (f32x4){0.f, 0.f, 0.f, 0.f};

  #define STAGE(kb, buf)                                                      \
    {                                                                         \
      _Pragma("unroll")                                                       \
      for (int q = 0; q < 2; ++q) {                                           \
        int row = q * 64 + w * 16 + srow;                                     \
        const u16* ga = xb + (size_t)(m0 + row) * 1024 + (kb) * 32 + skcol;   \
        gl_lds16(ga, &At[buf][q * 2048 + w * 512]);                           \
        const u16* gb = wbase + (size_t)(n0 + row) * 1024 + (kb) * 32 + skcol;\
        gl_lds16(gb, &Bt[buf][q * 2048 + w * 512]);                           \
      }                                                                       \
    }

  STAGE(0, 0);
  for (int kb = 0; kb < 32; ++kb) {
    int cur = kb & 1;
    __syncthreads();                           // drains staging of tile kb
    if (kb + 1 < 32) STAGE(kb + 1, cur ^ 1);
    short8v a[4], bf[4];
    #pragma unroll
    for (int m = 0; m < 4; ++m) {
      int row = wr * 64 + m * 16 + (l & 15);
      a[m] = *(const short8v*)&At[cur][row * 32 + (l >> 4) * 8];
    }
    #pragma unroll
    for (int n = 0; n < 4; ++n) {
      int row = wc * 64 + n * 16 + (l & 15);
      bf[n] = *(const short8v*)&Bt[cur][row * 32 + (l >> 4) * 8];
    }
    #pragma unroll
    for (int m = 0; m < 4; ++m)
      #pragma unroll
      for (int n = 0; n < 4; ++n)
        acc[m][n] = __builtin_amdgcn_mfma_f32_16x16x32_bf16(a[m], bf[n],
                                                            acc[m][n], 0, 0, 0);
  }
  #undef STAGE

  int ibase = m0 + wr * 64 + ((l >> 4) << 2);
  int jbase = n0 + wc * 64 + (l & 15);
  #pragma unroll
  for (int m = 0; m < 4; ++m) {
    #pragma unroll
    for (int n = 0; n < 4; ++n) {
      int j = jbase + n * 16;
      #pragma unroll
      for (int r = 0; r < 4; ++r) {
        int i = ibase + m * 16 + r;
        float v = acc[m][n][r];
        if (j < 1024) {
          delta[(size_t)i * D_ + j] = softplusf(v + delta_b[j] + dt_bias[j]);
        } else if (j < 1040) {
          Bm[i * N_ + (j - 1024)] = v + B_b[j - 1024];
        } else if (j < NCOLS) {
          Cm[i * N_ + (j - 1040)] = v + C_b[j - 1040];
        }
      }
    }
  }
}

// ---------------- K6: scan pass 1 — per-chunk local scan + decay product -----
__global__ __launch_bounds__(256) void k_scan1(const float* __restrict__ x,
    const float* __restrict__ sel, const float* __restrict__ delta,
    const float* __restrict__ Bm, const float* __restrict__ A_log,
    float* __restrict__ prodA, float* __restrict__ hend) {
  int gid = blockIdx.x * 256 + threadIdx.x;   // (b*CCH + c)*D_ + d
  int d = gid & (D_ - 1);
  int b = gid >> 16;                          // / (CCH*D_)
  int c = (gid >> 10) & (CCH - 1);
  float A[N_], rA[N_];
  unsigned smallm = 0;
  #pragma unroll
  for (int n = 0; n < N_; ++n) {
    float a = -__expf(A_log[d * N_ + n]);
    A[n] = a;
    rA[n] = 1.f / a;
    if (fabsf(a) < 1e-6f) smallm |= (1u << n);
  }
  float selv = sel[b * D_ + d];
  float h[N_], p[N_];
  #pragma unroll
  for (int n = 0; n < N_; ++n) { h[n] = 0.f; p[n] = 1.f; }
  int t0 = c * TCH;
  #pragma unroll 2
  for (int s = 0; s < TCH; ++s) {
    int row = b * L_ + t0 + s;
    size_t idx = (size_t)row * D_ + d;
    float dlt = delta[idx];
    float xv = x[idx] * selv;
    const float4* bmp = (const float4*)(Bm + (size_t)row * N_);
    float4 q0 = bmp[0], q1 = bmp[1], q2 = bmp[2], q3 = bmp[3];
    float bmv[N_] = {q0.x,q0.y,q0.z,q0.w, q1.x,q1.y,q1.z,q1.w,
                     q2.x,q2.y,q2.z,q2.w, q3.x,q3.y,q3.z,q3.w};
    #pragma unroll
    for (int n = 0; n < N_; ++n) {
      float Ad = __expf(A[n] * dlt);
      float f = ((smallm >> n) & 1u) ? dlt : (Ad - 1.f) * rA[n];
      h[n] = Ad * h[n] + (f * bmv[n]) * xv;
      p[n] *= Ad;
    }
  }
  float4* pp = (float4*)(prodA + (size_t)gid * N_);
  float4* hp = (float4*)(hend + (size_t)gid * N_);
  pp[0] = make_float4(p[0], p[1], p[2], p[3]);
  pp[1] = make_float4(p[4], p[5], p[6], p[7]);
  pp[2] = make_float4(p[8], p[9], p[10], p[11]);
  pp[3] = make_float4(p[12], p[13], p[14], p[15]);
  hp[0] = make_float4(h[0], h[1], h[2], h[3]);
  hp[1] = make_float4(h[4], h[5], h[6], h[7]);
  hp[2] = make_float4(h[8], h[9], h[10], h[11]);
  hp[3] = make_float4(h[12], h[13], h[14], h[15]);
}

// ---------------- K7: scan pass 2 — cross-chunk prefix (per b,d,n) -----------
__global__ __launch_bounds__(256) void k_scan2(const float* __restrict__ prodA,
    const float* __restrict__ hend, float* __restrict__ hin) {
  int gid = blockIdx.x * 256 + threadIdx.x;   // over B*D*N = 32768
  int b = gid >> 14;
  int rem = gid & 16383;                      // d*N + n
  float H = 0.f;
  for (int c = 0; c < CCH; ++c) {
    size_t idx = ((size_t)(b * CCH + c) << 14) + rem;
    hin[idx] = H;                             // carry-in for chunk c
    H = prodA[idx] * H + hend[idx];
  }
}

// ---------------- K8: scan pass 3 — re-scan with carry-in, emit y ------------
__global__ __launch_bounds__(256) void k_scan3(const float* __restrict__ x,
    const float* __restrict__ sel, const float* __restrict__ delta,
    const float* __restrict__ Bm, const float* __restrict__ Cm,
    const float* __restrict__ A_log, const float* __restrict__ hin,
    float* __restrict__ out) {
  int gid = blockIdx.x * 256 + threadIdx.x;
  int d = gid & (D_ - 1);
  int b = gid >> 16;
  int c = (gid >> 10) & (CCH - 1);
  float A[N_], rA[N_];
  unsigned smallm = 0;
  #pragma unroll
  for (int n = 0; n < N_; ++n) {
    float a = -__expf(A_log[d * N_ + n]);
    A[n] = a;
    rA[n] = 1.f / a;
    if (fabsf(a) < 1e-6f) smallm |= (1u << n);
  }
  float selv = sel[b * D_ + d];
  float h[N_];
  {
    const float4* hp = (const float4*)(hin + (size_t)gid * N_);
    float4 v0 = hp[0], v1 = hp[1], v2 = hp[2], v3 = hp[3];
    h[0]=v0.x; h[1]=v0.y; h[2]=v0.z; h[3]=v0.w;
    h[4]=v1.x; h[5]=v1.y; h[6]=v1.z; h[7]=v1.w;
    h[8]=v2.x; h[9]=v2.y; h[10]=v2.z; h[11]=v2.w;
    h[12]=v3.x; h[13]=v3.y; h[14]=v3.z; h[15]=v3.w;
  }
  int t0 = c * TCH;
  #pragma unroll 2
  for (int s = 0; s < TCH; ++s) {
    int row = b * L_ + t0 + s;
    size_t idx = (size_t)row * D_ + d;
    float dlt = delta[idx];
    float xv = x[idx] * selv;
    const float4* bmp = (const float4*)(Bm + (size_t)row * N_);
    float4 q0 = bmp[0], q1 = bmp[1], q2 = bmp[2], q3 = bmp[3];
    float bmv[N_] = {q0.x,q0.y,q0.z,q0.w, q1.x,q1.y,q1.z,q1.w,
                     q2.x,q2.y,q2.z,q2.w, q3.x,q3.y,q3.z,q3.w};
    const float4* cmp = (const float4*)(Cm + (size_t)row * N_);
    float4 r0 = cmp[0], r1 = cmp[1], r2 = cmp[2], r3 = cmp[3];
    float cmv[N_] = {r0.x,r0.y,r0.z,r0.w, r1.x,r1.y,r1.z,r1.w,
                     r2.x,r2.y,r2.z,r2.w, r3.x,r3.y,r3.z,r3.w};
    float y = 0.f;
    #pragma unroll
    for (int n = 0; n < N_; ++n) {
      float Ad = __expf(A[n] * dlt);
      float f = ((smallm >> n) & 1u) ? dlt : (Ad - 1.f) * rA[n];
      h[n] = Ad * h[n] + (f * bmv[n]) * xv;
      y += h[n] * cmv[n];
    }
    out[idx] = y;
  }
}

extern "C" void kernel_launch(void* const* d_in, const int* in_sizes, int n_in,
                              void* d_out, int out_size, void* d_ws, size_t ws_size,
                              hipStream_t stream) {
  const float* x       = (const float*)d_in[0];
  const float* deltaW  = (const float*)d_in[1];
  const float* deltab  = (const float*)d_in[2];
  const float* B_W     = (const float*)d_in[3];
  const float* B_b     = (const float*)d_in[4];
  const float* C_W     = (const float*)d_in[5];
  const float* C_b     = (const float*)d_in[6];
  const float* A_log   = (const float*)d_in[7];
  const float* dt_bias = (const float*)d_in[8];
  const float* tau     = (const float*)d_in[9];
  const float* Wi_W    = (const float*)d_in[10];
  const float* Wi_b    = (const float*)d_in[11];
  const float* Wr_W    = (const float*)d_in[12];
  const float* sel_W   = (const float*)d_in[13];
  const float* sel_b   = (const float*)d_in[14];
  const float* h0      = (const float*)d_in[15];
  float* out = (float*)d_out;

  float* ws    = (float*)d_ws;          // ~42.7 MB total
  float* delta = ws;                    // 4,194,304
  float* part  = delta + 4194304;       // 65,536
  float* newh  = part + 65536;          // 64
  float* selp  = newh + 64;             // 2,048
  float* Bm    = selp + 2048;           // 65,536
  float* Cm    = Bm + 65536;            // 65,536
  float* prodA = Cm + 65536;            // 2,097,152  (aliases xb)
  float* hend  = prodA + 2097152;       // 2,097,152  (aliases Wp)
  float* hin   = hend + 2097152;        // 2,097,152
  u16* xb = (u16*)prodA;                // 4096*1024 bf16 (8 MB)  — dead before scan1
  u16* Wp = (u16*)hend;                 // 2*1152*1024 bf16 (4.7 MB) — dead before scan1

  hipLaunchKernelGGL(k_gc_partial, dim3(64), dim3(256), 0, stream, x, part);
  hipLaunchKernelGGL(k_newh, dim3(1), dim3(256), 0, stream,
                     part, Wi_W, Wi_b, Wr_W, tau, h0, newh);
  hipLaunchKernelGGL(k_sel, dim3(8), dim3(256), 0, stream,
                     newh, sel_W, sel_b, selp);
  hipLaunchKernelGGL(k_pack_x, dim3(2048), dim3(256), 0, stream, x, xb);
  hipLaunchKernelGGL(k_pack_w, dim3(576, 2), dim3(256), 0, stream,
                     deltaW, B_W, C_W, selp, Wp);
  hipLaunchKernelGGL(k_gemm, dim3(32, 9), dim3(256), 0, stream,
                     xb, Wp, deltab, dt_bias, B_b, C_b, delta, Bm, Cm);
  hipLaunchKernelGGL(k_scan1, dim3(512), dim3(256), 0, stream,
                     x, selp, delta, Bm, A_log, prodA, hend);
  hipLaunchKernelGGL(k_scan2, dim3(128), dim3(256), 0, stream,
                     prodA, hend, hin);
  hipLaunchKernelGGL(k_scan3, dim3(512), dim3(256), 0, stream,
                     x, selp, delta, Bm, Cm, A_log, hin, out);
}

// Round 3
// 174.230 us; speedup vs baseline: 1.9202x; 1.3739x over previous
//
#include <hip/hip_runtime.h>
#include <hip/hip_bf16.h>
#include <math.h>

#define B_ 2
#define L_ 2048
#define D_ 1024
#define N_ 16
#define CCH 64   // chunks over L
#define TCH 32   // chunk length  (CCH*TCH == L_)
#define NCOLS 1056   // D_ + 2*N_
#define NPAD  1088   // 17 * 64

typedef unsigned short u16;
typedef __attribute__((ext_vector_type(8))) short short8v;
typedef __attribute__((ext_vector_type(8))) unsigned short ushort8v;
typedef __attribute__((ext_vector_type(4))) float f32x4;

__device__ __forceinline__ float softplusf(float z) {
  return fmaxf(z, 0.f) + log1pf(__expf(-fabsf(z)));
}

__device__ __forceinline__ u16 bf16rne(float f) {
  union { float f; unsigned u; } c; c.f = f;
  unsigned u = c.u;
  u += 0x7fffu + ((u >> 16) & 1u);
  return (u16)(u >> 16);
}

// LDS byte offset hoisted to SGPR via readfirstlane (HK technique: avoids
// divergent-LDS-pointer waterfall around the M0-based LDS-DMA).
__device__ __forceinline__ void gl_lds16(const void* g, const u16* lds_base,
                                         int byte_off) {
  byte_off = __builtin_amdgcn_readfirstlane(byte_off);
  __builtin_amdgcn_global_load_lds(
      (const __attribute__((address_space(1))) void*)g,
      (__attribute__((address_space(3))) void*)((const char*)lds_base + byte_off),
      16, 0, 0);
}

// ---------------- K1: partial sums over t-chunks for gc = mean_L(x) ----------
__global__ __launch_bounds__(256) void k_gc_partial(const float* __restrict__ x,
                                                    float* __restrict__ part) {
  int blk = blockIdx.x;            // b*32 + lc
  int b = blk >> 5, lc = blk & 31;
  int tid = threadIdx.x;
  float s0 = 0.f, s1 = 0.f, s2 = 0.f, s3 = 0.f;
  int tbase = b * L_ + lc * 64;
  for (int s = 0; s < 64; ++s) {
    const float* row = x + (size_t)(tbase + s) * D_;
    s0 += row[tid];
    s1 += row[tid + 256];
    s2 += row[tid + 512];
    s3 += row[tid + 768];
  }
  float* p = part + (size_t)blk * D_;
  p[tid] = s0; p[tid + 256] = s1; p[tid + 512] = s2; p[tid + 768] = s3;
}

// ---------------- K2: reduce partials -> gc, liquid scaler -> new_h [B,N] ----
__global__ __launch_bounds__(256) void k_newh(const float* __restrict__ part,
    const float* __restrict__ Wi_W, const float* __restrict__ Wi_b,
    const float* __restrict__ Wr_W, const float* __restrict__ tau,
    const float* __restrict__ h0, float* __restrict__ newh) {
  __shared__ float gcs[B_ * D_];
  int tid = threadIdx.x;
  for (int idx = tid; idx < B_ * D_; idx += 256) {
    int b = idx >> 10, d = idx & (D_ - 1);
    float s = 0.f;
    for (int lc = 0; lc < 32; ++lc) s += part[(size_t)((b << 5) | lc) * D_ + d];
    gcs[idx] = s * (1.f / L_);
  }
  __syncthreads();
  if (tid < B_ * N_) {
    int b = tid >> 4, n = tid & 15;
    float inp = Wi_b[n];
    const float* g = gcs + b * D_;
    const float* w = Wi_W + n * D_;
    for (int d = 0; d < D_; d += 4) {
      float4 gv = *(const float4*)(g + d);
      float4 wv = *(const float4*)(w + d);
      inp += gv.x * wv.x + gv.y * wv.y + gv.z * wv.z + gv.w * wv.w;
    }
    float rec = 0.f;
    for (int m = 0; m < N_; ++m) rec += h0[m] * Wr_W[n * N_ + m];
    float th = tanhf(inp + rec);
    float tc = fminf(fmaxf(tau[n], 0.1f), 10.f);
    float cur = h0[n];
    newh[tid] = cur + 0.1f * ((th - cur) / tc);   // DT = 0.1
  }
}

// ---------------- K3: sel[b,d] = sigmoid(new_h @ sel_W.T + sel_b) ------------
__global__ __launch_bounds__(256) void k_sel(const float* __restrict__ newh,
    const float* __restrict__ sel_W, const float* __restrict__ sel_b,
    float* __restrict__ sel) {
  int gid = blockIdx.x * 256 + threadIdx.x;   // over B*D
  int b = gid >> 10, d = gid & (D_ - 1);
  const float* w = sel_W + d * N_;
  const float* h = newh + b * N_;
  float z = sel_b[d];
  #pragma unroll
  for (int n = 0; n < N_; n += 4) {
    float4 wv = *(const float4*)(w + n);
    z += h[n] * wv.x + h[n + 1] * wv.y + h[n + 2] * wv.z + h[n + 3] * wv.w;
  }
  sel[gid] = 1.f / (1.f + __expf(-z));
}

// ---------------- K4a: pack x -> bf16 ----------------------------------------
__global__ __launch_bounds__(256) void k_pack_x(const float* __restrict__ x,
                                                u16* __restrict__ xb) {
  int gid = blockIdx.x * 256 + threadIdx.x;    // 524288 threads, 8 elems each
  const float4* xp = (const float4*)x + (size_t)gid * 2;
  float4 v0 = xp[0], v1 = xp[1];
  ushort8v r;
  r[0] = bf16rne(v0.x); r[1] = bf16rne(v0.y);
  r[2] = bf16rne(v0.z); r[3] = bf16rne(v0.w);
  r[4] = bf16rne(v1.x); r[5] = bf16rne(v1.y);
  r[6] = bf16rne(v1.z); r[7] = bf16rne(v1.w);
  *(ushort8v*)(xb + (size_t)gid * 8) = r;
}

// ---------------- K4b: pack [delta_W; B_W; C_W] * sel(b) -> bf16 -------------
__global__ __launch_bounds__(256) void k_pack_w(const float* __restrict__ dW,
    const float* __restrict__ B_W, const float* __restrict__ C_W,
    const float* __restrict__ sel, u16* __restrict__ Wp) {
  int gid = blockIdx.x * 256 + threadIdx.x;    // 139264 threads, 8 elems each
  int b = blockIdx.y;
  size_t e = (size_t)gid * 8;                  // < 1114112
  int nn = (int)(e >> 10);
  int k = (int)(e & 1023);
  ushort8v r;
  if (nn < NCOLS) {
    const float* src = (nn < 1024) ? dW + (size_t)nn * 1024
                     : (nn < 1040) ? B_W + (size_t)(nn - 1024) * 1024
                                   : C_W + (size_t)(nn - 1040) * 1024;
    float4 s0 = *(const float4*)(src + k);
    float4 s1 = *(const float4*)(src + k + 4);
    const float* sp = sel + b * D_ + k;
    float4 e0 = *(const float4*)sp;
    float4 e1 = *(const float4*)(sp + 4);
    r[0] = bf16rne(s0.x * e0.x); r[1] = bf16rne(s0.y * e0.y);
    r[2] = bf16rne(s0.z * e0.z); r[3] = bf16rne(s0.w * e0.w);
    r[4] = bf16rne(s1.x * e1.x); r[5] = bf16rne(s1.y * e1.y);
    r[6] = bf16rne(s1.z * e1.z); r[7] = bf16rne(s1.w * e1.w);
  } else {
    r = (ushort8v)0;
  }
  *(ushort8v*)(Wp + (size_t)b * (NPAD * 1024) + e) = r;
}

// ---------------- K5: MFMA GEMM  C[4096 x 1088] = xb @ Wp^T ------------------
// 64x64 tile, BK=64, 4 waves (2x2), double-buffered gl_lds staging with
// XOR-swizzled source (rule #21: linear LDS dest + swizzled global src +
// same swizzle on ds_read). Grid 64x17 = 1088 blocks (~4.3/CU).
__global__ __launch_bounds__(256) void k_gemm(
    const u16* __restrict__ xb, const u16* __restrict__ Wp,
    const float* __restrict__ delta_b, const float* __restrict__ dt_bias,
    const float* __restrict__ B_b, const float* __restrict__ C_b,
    float* __restrict__ delta, float* __restrict__ Bm, float* __restrict__ Cm) {
  __shared__ __align__(16) u16 At[2][64 * 64];   // [buf][row*64 + col]
  __shared__ __align__(16) u16 Bt[2][64 * 64];
  int m0 = blockIdx.x * 64;
  int n0 = blockIdx.y * 64;
  int batch = blockIdx.x >> 5;                   // 32 m-tiles per batch
  const u16* wbase = Wp + (size_t)batch * (NPAD * 1024);
  int tid = threadIdx.x;
  int w = tid >> 6, l = tid & 63;
  int wr = w >> 1, wc = w & 1;
  int srow = l >> 3;                             // 0..7 (== row&7 at staging)
  int sslot = l & 7;                             // physical 16B slot in row
  int ssl = sslot ^ srow;                        // swizzled logical slot

  f32x4 acc[2][2];
  #pragma unroll
  for (int m = 0; m < 2; ++m)
    #pragma unroll
    for (int n = 0; n < 2; ++n)
      acc[m][n] = (f32x4){0.f, 0.f, 0.f, 0.f};

  // wave w stages rows [w*16, w*16+16): q*8+srow; lane -> linear LDS slot.
  #define STAGE(kb, buf)                                                       \
    {                                                                          \
      _Pragma("unroll")                                                        \
      for (int q = 0; q < 2; ++q) {                                            \
        int row = w * 16 + q * 8 + srow;                                       \
        const u16* ga = xb + (size_t)(m0 + row) * 1024 + (kb) * 64 + ssl * 8;  \
        gl_lds16(ga, &At[0][0], (buf) * 8192 + w * 2048 + q * 1024);           \
        const u16* gb = wbase + (size_t)(n0 + row) * 1024 + (kb) * 64 + ssl * 8;\
        gl_lds16(gb, &Bt[0][0], (buf) * 8192 + w * 2048 + q * 1024);           \
      }                                                                        \
    }

  STAGE(0, 0);
  int lrow16 = l & 15;
  int lk = l >> 4;                               // 0..3
  for (int kb = 0; kb < 16; ++kb) {
    int cur = kb & 1;
    __syncthreads();                             // staging of tile kb complete
    if (kb + 1 < 16) STAGE(kb + 1, cur ^ 1);
    short8v a[2][2], bq[2][2];
    #pragma unroll
    for (int m = 0; m < 2; ++m) {
      int r = wr * 32 + m * 16 + lrow16;
      #pragma unroll
      for (int ks = 0; ks < 2; ++ks) {
        int cp = (ks * 4 + lk) ^ (l & 7);        // swizzled physical slot
        a[m][ks] = *(const short8v*)((const char*)&At[cur][0] + r * 128 + cp * 16);
      }
    }
    #pragma unroll
    for (int n = 0; n < 2; ++n) {
      int r = wc * 32 + n * 16 + lrow16;
      #pragma unroll
      for (int ks = 0; ks < 2; ++ks) {
        int cp = (ks * 4 + lk) ^ (l & 7);
        bq[n][ks] = *(const short8v*)((const char*)&Bt[cur][0] + r * 128 + cp * 16);
      }
    }
    #pragma unroll
    for (int m = 0; m < 2; ++m)
      #pragma unroll
      for (int n = 0; n < 2; ++n)
        #pragma unroll
        for (int ks = 0; ks < 2; ++ks)
          acc[m][n] = __builtin_amdgcn_mfma_f32_16x16x32_bf16(a[m][ks], bq[n][ks],
                                                              acc[m][n], 0, 0, 0);
  }
  #undef STAGE

  int ibase = m0 + wr * 32 + (lk << 2);
  int jbase = n0 + wc * 32 + lrow16;
  #pragma unroll
  for (int m = 0; m < 2; ++m) {
    #pragma unroll
    for (int n = 0; n < 2; ++n) {
      int j = jbase + n * 16;
      #pragma unroll
      for (int r = 0; r < 4; ++r) {
        int i = ibase + m * 16 + r;
        float v = acc[m][n][r];
        if (j < 1024) {
          delta[(size_t)i * D_ + j] = softplusf(v + delta_b[j] + dt_bias[j]);
        } else if (j < 1040) {
          Bm[i * N_ + (j - 1024)] = v + B_b[j - 1024];
        } else if (j < NCOLS) {
          Cm[i * N_ + (j - 1040)] = v + C_b[j - 1040];
        }
      }
    }
  }
}

// ---------------- K6: scan pass 1 — per-chunk local scan + decay product -----
__global__ __launch_bounds__(256) void k_scan1(const float* __restrict__ x,
    const float* __restrict__ sel, const float* __restrict__ delta,
    const float* __restrict__ Bm, const float* __restrict__ A_log,
    float* __restrict__ prodA, float* __restrict__ hend) {
  int gid = blockIdx.x * 256 + threadIdx.x;   // (b*CCH + c)*D_ + d
  int d = gid & (D_ - 1);
  int b = gid >> 16;                          // / (CCH*D_)
  int c = (gid >> 10) & (CCH - 1);
  float A[N_], rA[N_];
  unsigned smallm = 0;
  #pragma unroll
  for (int n = 0; n < N_; ++n) {
    float a = -__expf(A_log[d * N_ + n]);
    A[n] = a;
    rA[n] = 1.f / a;
    if (fabsf(a) < 1e-6f) smallm |= (1u << n);
  }
  float selv = sel[b * D_ + d];
  float h[N_], p[N_];
  #pragma unroll
  for (int n = 0; n < N_; ++n) { h[n] = 0.f; p[n] = 1.f; }
  int t0 = c * TCH;
  #pragma unroll 2
  for (int s = 0; s < TCH; ++s) {
    int row = b * L_ + t0 + s;
    size_t idx = (size_t)row * D_ + d;
    float dlt = delta[idx];
    float xv = x[idx] * selv;
    const float4* bmp = (const float4*)(Bm + (size_t)row * N_);
    float4 q0 = bmp[0], q1 = bmp[1], q2 = bmp[2], q3 = bmp[3];
    float bmv[N_] = {q0.x,q0.y,q0.z,q0.w, q1.x,q1.y,q1.z,q1.w,
                     q2.x,q2.y,q2.z,q2.w, q3.x,q3.y,q3.z,q3.w};
    #pragma unroll
    for (int n = 0; n < N_; ++n) {
      float Ad = __expf(A[n] * dlt);
      float f = ((smallm >> n) & 1u) ? dlt : (Ad - 1.f) * rA[n];
      h[n] = Ad * h[n] + (f * bmv[n]) * xv;
      p[n] *= Ad;
    }
  }
  float4* pp = (float4*)(prodA + (size_t)gid * N_);
  float4* hp = (float4*)(hend + (size_t)gid * N_);
  pp[0] = make_float4(p[0], p[1], p[2], p[3]);
  pp[1] = make_float4(p[4], p[5], p[6], p[7]);
  pp[2] = make_float4(p[8], p[9], p[10], p[11]);
  pp[3] = make_float4(p[12], p[13], p[14], p[15]);
  hp[0] = make_float4(h[0], h[1], h[2], h[3]);
  hp[1] = make_float4(h[4], h[5], h[6], h[7]);
  hp[2] = make_float4(h[8], h[9], h[10], h[11]);
  hp[3] = make_float4(h[12], h[13], h[14], h[15]);
}

// ---------------- K7: scan pass 2 — cross-chunk prefix (per b,d,n) -----------
__global__ __launch_bounds__(256) void k_scan2(const float* __restrict__ prodA,
    const float* __restrict__ hend, float* __restrict__ hin) {
  int gid = blockIdx.x * 256 + threadIdx.x;   // over B*D*N = 32768
  int b = gid >> 14;
  int rem = gid & 16383;                      // d*N + n
  float H = 0.f;
  for (int c = 0; c < CCH; ++c) {
    size_t idx = ((size_t)(b * CCH + c) << 14) + rem;
    hin[idx] = H;                             // carry-in for chunk c
    H = prodA[idx] * H + hend[idx];
  }
}

// ---------------- K8: scan pass 3 — re-scan with carry-in, emit y ------------
__global__ __launch_bounds__(256) void k_scan3(const float* __restrict__ x,
    const float* __restrict__ sel, const float* __restrict__ delta,
    const float* __restrict__ Bm, const float* __restrict__ Cm,
    const float* __restrict__ A_log, const float* __restrict__ hin,
    float* __restrict__ out) {
  int gid = blockIdx.x * 256 + threadIdx.x;
  int d = gid & (D_ - 1);
  int b = gid >> 16;
  int c = (gid >> 10) & (CCH - 1);
  float A[N_], rA[N_];
  unsigned smallm = 0;
  #pragma unroll
  for (int n = 0; n < N_; ++n) {
    float a = -__expf(A_log[d * N_ + n]);
    A[n] = a;
    rA[n] = 1.f / a;
    if (fabsf(a) < 1e-6f) smallm |= (1u << n);
  }
  float selv = sel[b * D_ + d];
  float h[N_];
  {
    const float4* hp = (const float4*)(hin + (size_t)gid * N_);
    float4 v0 = hp[0], v1 = hp[1], v2 = hp[2], v3 = hp[3];
    h[0]=v0.x; h[1]=v0.y; h[2]=v0.z; h[3]=v0.w;
    h[4]=v1.x; h[5]=v1.y; h[6]=v1.z; h[7]=v1.w;
    h[8]=v2.x; h[9]=v2.y; h[10]=v2.z; h[11]=v2.w;
    h[12]=v3.x; h[13]=v3.y; h[14]=v3.z; h[15]=v3.w;
  }
  int t0 = c * TCH;
  #pragma unroll 2
  for (int s = 0; s < TCH; ++s) {
    int row = b * L_ + t0 + s;
    size_t idx = (size_t)row * D_ + d;
    float dlt = delta[idx];
    float xv = x[idx] * selv;
    const float4* bmp = (const float4*)(Bm + (size_t)row * N_);
    float4 q0 = bmp[0], q1 = bmp[1], q2 = bmp[2], q3 = bmp[3];
    float bmv[N_] = {q0.x,q0.y,q0.z,q0.w, q1.x,q1.y,q1.z,q1.w,
                     q2.x,q2.y,q2.z,q2.w, q3.x,q3.y,q3.z,q3.w};
    const float4* cmp = (const float4*)(Cm + (size_t)row * N_);
    float4 r0 = cmp[0], r1 = cmp[1], r2 = cmp[2], r3 = cmp[3];
    float cmv[N_] = {r0.x,r0.y,r0.z,r0.w, r1.x,r1.y,r1.z,r1.w,
                     r2.x,r2.y,r2.z,r2.w, r3.x,r3.y,r3.z,r3.w};
    float y = 0.f;
    #pragma unroll
    for (int n = 0; n < N_; ++n) {
      float Ad = __expf(A[n] * dlt);
      float f = ((smallm >> n) & 1u) ? dlt : (Ad - 1.f) * rA[n];
      h[n] = Ad * h[n] + (f * bmv[n]) * xv;
      y += h[n] * cmv[n];
    }
    out[idx] = y;
  }
}

extern "C" void kernel_launch(void* const* d_in, const int* in_sizes, int n_in,
                              void* d_out, int out_size, void* d_ws, size_t ws_size,
                              hipStream_t stream) {
  const float* x       = (const float*)d_in[0];
  const float* deltaW  = (const float*)d_in[1];
  const float* deltab  = (const float*)d_in[2];
  const float* B_W     = (const float*)d_in[3];
  const float* B_b     = (const float*)d_in[4];
  const float* C_W     = (const float*)d_in[5];
  const float* C_b     = (const float*)d_in[6];
  const float* A_log   = (const float*)d_in[7];
  const float* dt_bias = (const float*)d_in[8];
  const float* tau     = (const float*)d_in[9];
  const float* Wi_W    = (const float*)d_in[10];
  const float* Wi_b    = (const float*)d_in[11];
  const float* Wr_W    = (const float*)d_in[12];
  const float* sel_W   = (const float*)d_in[13];
  const float* sel_b   = (const float*)d_in[14];
  const float* h0      = (const float*)d_in[15];
  float* out = (float*)d_out;

  float* ws    = (float*)d_ws;          // ~42.7 MB total
  float* delta = ws;                    // 4,194,304
  float* part  = delta + 4194304;       // 65,536
  float* newh  = part + 65536;          // 64
  float* selp  = newh + 64;             // 2,048
  float* Bm    = selp + 2048;           // 65,536
  float* Cm    = Bm + 65536;            // 65,536
  float* prodA = Cm + 65536;            // 2,097,152  (aliases xb)
  float* hend  = prodA + 2097152;       // 2,097,152  (aliases Wp)
  float* hin   = hend + 2097152;        // 2,097,152
  u16* xb = (u16*)prodA;                // 4096*1024 bf16 (8 MB)  — dead before scan1
  u16* Wp = (u16*)hend;                 // 2*1088*1024 bf16 (4.5 MB) — dead before scan1

  hipLaunchKernelGGL(k_gc_partial, dim3(64), dim3(256), 0, stream, x, part);
  hipLaunchKernelGGL(k_newh, dim3(1), dim3(256), 0, stream,
                     part, Wi_W, Wi_b, Wr_W, tau, h0, newh);
  hipLaunchKernelGGL(k_sel, dim3(8), dim3(256), 0, stream,
                     newh, sel_W, sel_b, selp);
  hipLaunchKernelGGL(k_pack_x, dim3(2048), dim3(256), 0, stream, x, xb);
  hipLaunchKernelGGL(k_pack_w, dim3(544, 2), dim3(256), 0, stream,
                     deltaW, B_W, C_W, selp, Wp);
  hipLaunchKernelGGL(k_gemm, dim3(64, 17), dim3(256), 0, stream,
                     xb, Wp, deltab, dt_bias, B_b, C_b, delta, Bm, Cm);
  hipLaunchKernelGGL(k_scan1, dim3(512), dim3(256), 0, stream,
                     x, selp, delta, Bm, A_log, prodA, hend);
  hipLaunchKernelGGL(k_scan2, dim3(128), dim3(256), 0, stream,
                     prodA, hend, hin);
  hipLaunchKernelGGL(k_scan3, dim3(512), dim3(256), 0, stream,
                     x, selp, delta, Bm, Cm, A_log, hin, out);
}